// Round 3
// baseline (27.239 us; speedup 1.0000x reference)
//
#include <hip/hip_runtime.h>
#include <math.h>

// ComparingLoss: s = sum_{i<j, disc(i,j)} (d_i + d_j), out = s/T
// s = sum_i d_i * c_i with the single canonical predicate (xi>xj)^(li>lj),
// valid for all j (both orientations agree for tie-free data; false at j==i).
//
// Single-kernel finish: each block contributes one deterministic integer
// atomicAdd of (fix<<10 | 1), where fix = round(partial * 2^18) and the low
// 10 bits count block arrivals (1024 blocks). The last arrival's return value
// already contains every other block's contribution, so it alone converts and
// writes out[0]. No fences, no partials array, no second kernel. The 8-byte
// accumulator is zeroed per call by hipMemsetAsync (capture-legal).

#define T_N    8192
#define BLK    256                 // threads per block
#define IPT    2                   // i-rows per thread
#define JC     128                 // j-chunk per block
#define NIB    (T_N / (BLK * IPT)) // 16 i-blocks
#define NJC    (T_N / JC)          // 64 j-chunks
#define NBLK   (NIB * NJC)         // 1024 blocks
#define FIXSCL 262144.0            // 2^18

__global__ __launch_bounds__(BLK) void pair_count_kernel(
    const float* __restrict__ x, const float* __restrict__ lab,
    unsigned long long* __restrict__ acc, float* __restrict__ out) {
  __shared__ float wsum[BLK / 64];

  const int tid = threadIdx.x;
  const int i0 = blockIdx.x * (BLK * IPT) + tid;   // second row at i0 + BLK
  const int j0 = blockIdx.y * JC;

  const float xi0 = x[i0];
  const float li0 = lab[i0];
  const float xi1 = x[i0 + BLK];
  const float li1 = lab[i0 + BLK];

  int c0 = 0, c1 = 0;
#pragma unroll 8
  for (int jj = 0; jj < JC; ++jj) {
    // j0+jj is wave-uniform -> scalar loads on the SMEM pipe
    const float xj = x[j0 + jj];
    const float lj = lab[j0 + jj];
    c0 += (int)((xi0 > xj) != (li0 > lj));
    c1 += (int)((xi1 > xj) != (li1 > lj));
  }

  float val = fabsf(xi0 - li0) * (float)c0 + fabsf(xi1 - li1) * (float)c1;

  // wave-64 tree reduce
#pragma unroll
  for (int off = 32; off >= 1; off >>= 1) val += __shfl_down(val, off, 64);

  const int wave = tid >> 6;
  if ((tid & 63) == 0) wsum[wave] = val;
  __syncthreads();

  if (tid == 0) {
    const float s = wsum[0] + wsum[1] + wsum[2] + wsum[3];   // >= 0
    const unsigned long long fix =
        (unsigned long long)((double)s * FIXSCL + 0.5);
    const unsigned long long add = (fix << 10) | 1ULL;
    const unsigned long long old = atomicAdd(acc, add);
    if ((old & 1023ULL) == 1023ULL) {          // last of NBLK arrivals
      const unsigned long long tot = old + add;  // final packed total
      const double s_all = (double)(tot >> 10) * (1.0 / FIXSCL);
      out[0] = (float)(s_all / (double)T_N);
    }
  }
}

extern "C" void kernel_launch(void* const* d_in, const int* in_sizes, int n_in,
                              void* d_out, int out_size, void* d_ws, size_t ws_size,
                              hipStream_t stream) {
  const float* x = (const float*)d_in[0];
  const float* lab = (const float*)d_in[1];
  float* out = (float*)d_out;
  unsigned long long* acc = (unsigned long long*)d_ws;

  hipMemsetAsync(d_ws, 0, sizeof(unsigned long long), stream);
  dim3 grid(NIB, NJC);
  pair_count_kernel<<<grid, BLK, 0, stream>>>(x, lab, acc, out);
}

// Round 4
// 14.884 us; speedup vs baseline: 1.8301x; 1.8301x over previous
//
#include <hip/hip_runtime.h>
#include <math.h>

// ComparingLoss: s = sum_{i<j, disc(i,j)} (d_i + d_j), out = s/T
// s = sum_i d_i * c_i, canonical predicate (xi>xj)^(li>lj) over ALL j
// (valid both orientations for tie-free data; false at j==i).
//
// R4: two deterministic kernels (R3's single-address atomic tail cost ~12us).
// Pair kernel: j-chunk staged in LDS as float2 (one ds_read_b64 broadcast per
// iter), amortized over IPT=4 i-rows. 1024 blocks -> 4 waves/SIMD.

#define T_N   8192
#define BLK   256                  // threads per block
#define IPT   4                    // i-rows per thread
#define JC    64                   // j-chunk per block
#define NIB   (T_N / (BLK * IPT))  // 8 i-blocks
#define NJC   (T_N / JC)           // 128 j-chunks
#define NPART (NIB * NJC)          // 1024 partials

__global__ __launch_bounds__(BLK) void pair_count_kernel(
    const float* __restrict__ x, const float* __restrict__ lab,
    float* __restrict__ partial) {
  __shared__ float2 js[JC];
  __shared__ float wsum[BLK / 64];

  const int tid = threadIdx.x;
  const int i0 = blockIdx.x * (BLK * IPT) + tid;  // rows i0 + k*BLK, k=0..3
  const int j0 = blockIdx.y * JC;

  if (tid < JC) js[tid] = make_float2(x[j0 + tid], lab[j0 + tid]);

  float xi[IPT], li[IPT];
#pragma unroll
  for (int k = 0; k < IPT; ++k) {
    xi[k] = x[i0 + k * BLK];
    li[k] = lab[i0 + k * BLK];
  }
  __syncthreads();

  int cnt[IPT] = {0, 0, 0, 0};
#pragma unroll 16
  for (int jj = 0; jj < JC; ++jj) {
    const float2 v = js[jj];  // broadcast ds_read_b64, conflict-free
#pragma unroll
    for (int k = 0; k < IPT; ++k)
      cnt[k] += (int)((xi[k] > v.x) != (li[k] > v.y));
  }

  float val = 0.f;
#pragma unroll
  for (int k = 0; k < IPT; ++k)
    val += fabsf(xi[k] - li[k]) * (float)cnt[k];

  // wave-64 tree reduce
#pragma unroll
  for (int off = 32; off >= 1; off >>= 1) val += __shfl_down(val, off, 64);

  const int wave = tid >> 6;
  if ((tid & 63) == 0) wsum[wave] = val;
  __syncthreads();

  if (tid == 0) {
    const float s = wsum[0] + wsum[1] + wsum[2] + wsum[3];
    partial[blockIdx.y * NIB + blockIdx.x] = s;
  }
}

__global__ __launch_bounds__(256) void reduce_kernel(
    const float* __restrict__ partial, float* __restrict__ out) {
  __shared__ double wsum[4];
  const int tid = threadIdx.x;
  // one float4 load per thread covers all 1024 partials at one load depth
  const float4 p = ((const float4*)partial)[tid];
  double s = (double)p.x + (double)p.y + (double)p.z + (double)p.w;
#pragma unroll
  for (int off = 32; off >= 1; off >>= 1) s += __shfl_down(s, off, 64);
  const int wave = tid >> 6;
  if ((tid & 63) == 0) wsum[wave] = s;
  __syncthreads();
  if (tid == 0) {
    const double total = wsum[0] + wsum[1] + wsum[2] + wsum[3];
    out[0] = (float)(total / (double)T_N);
  }
}

extern "C" void kernel_launch(void* const* d_in, const int* in_sizes, int n_in,
                              void* d_out, int out_size, void* d_ws, size_t ws_size,
                              hipStream_t stream) {
  const float* x = (const float*)d_in[0];
  const float* lab = (const float*)d_in[1];
  float* out = (float*)d_out;
  float* partial = (float*)d_ws;  // NPART floats = 4 KiB

  dim3 grid(NIB, NJC);
  pair_count_kernel<<<grid, BLK, 0, stream>>>(x, lab, partial);
  reduce_kernel<<<1, 256, 0, stream>>>(partial, out);
}